// Round 10
// baseline (427.096 us; speedup 1.0000x reference)
//
#include <hip/hip_runtime.h>

typedef _Float16 f16;
typedef _Float16 f16x2 __attribute__((ext_vector_type(2)));
typedef _Float16 f16x4 __attribute__((ext_vector_type(4)));
typedef _Float16 f16x8 __attribute__((ext_vector_type(8)));
typedef float    f32x4 __attribute__((ext_vector_type(4)));

// Geometry:
//   x:   (4,128,64,64) f32     p5: (128,21,64,64) f32
//   p6:  (128,21,128)  f32     out:(4,128,64,64)  f32
// Workspace:
//   xk  [3][4][128][82][64] f16 = x*(1/8), pre-shifted per kc, zero-padded rows
//   t6T [4][128][2688]      f16 = p6 * t3, d-major
//   t3p [8][4][11][128][128] f16 = split-K Gram partials, rki 0..10 ONLY
//        (t3[c,rk,d] = t3[d,20-rk,c] exactly — lag symmetry; ep mirrors rk>=11)
//   t8p [8s][4][64][128][64] f16 = split-K out partials (s=js*4+g), ALIASES t3p
#define XROWS 82
#define XSTR  (XROWS * 64)
#define XK_ELEMS (3u * 4u * 128u * (unsigned)XSTR)
static const size_t T6T_OFF   = (size_t)XK_ELEMS * 2;                 // 16.12 MB
static const size_t T6T_BYTES = (size_t)4 * 128 * 2688 * 2;           // 2.75 MB
static const size_t T3P_OFF   = T6T_OFF + T6T_BYTES;
static const size_t T8P_OFF   = T3P_OFF;   // t3p dead before outp writes t8p

__device__ __forceinline__ void gl16(const f16* g, f16* l) {
  __builtin_amdgcn_global_load_lds((const __attribute__((address_space(1))) void*)g,
                                   (__attribute__((address_space(3))) void*)l, 16, 0, 0);
}

// ---------------------------------------------------------------- prep (round-8 version: float2 loads)
__global__ __launch_bounds__(256) void prep_kernel(const float* __restrict__ x,
                                                   f16* __restrict__ xk) {
  unsigned p = blockIdx.x * 256u + threadIdx.x;
  unsigned total = 3u * 4u * 128u * 82u * 32u;
  if (p >= total) return;
  unsigned wp   = p & 31u;
  unsigned row  = (p >> 5) % 82u;
  unsigned rest = p / (32u * 82u);
  unsigned c    = rest & 127u;
  unsigned rest2 = rest >> 7;
  unsigned n    = rest2 & 3u;
  unsigned kc   = rest2 >> 2;
  int hsrc = (int)row - 9;
  int wsrc = (int)(wp * 2u) + 2 * (int)kc - 2;
  f16x2 v; v.x = (f16)0.f; v.y = (f16)0.f;
  if (hsrc >= 0 && hsrc < 64 && wsrc >= 0 && wsrc < 64) {
    const float2* src = (const float2*)(x + (((size_t)(n * 128u + c) * 64u + (unsigned)hsrc) * 64u + (unsigned)wsrc));
    float2 xv = *src;
    v.x = (f16)(xv.x * 0.125f);
    v.y = (f16)(xv.y * 0.125f);
  }
  ((f16x2*)xk)[p] = v;
}

// ---------------------------------------------------------------- gram (LDS-staged, rki 0..10, split-K)
// grid 704 = n(4)*rki(11)*cseg(2)*ks(8); block 256 (4 waves 2x2), tile 64c x 128d, K-slice 512, 8 steps.
__global__ __launch_bounds__(256, 3) void gram_kernel(const f16* __restrict__ xk,
                                                      f16* __restrict__ t3p) {
  __shared__ f16 gl[2 * 12288];

  unsigned b    = blockIdx.x;
  unsigned ks   = b & 7u;
  unsigned cseg = (b >> 3) & 1u;
  unsigned rki  = (b >> 4) % 11u;
  unsigned n    = b / 176u;
  unsigned r    = rki / 3u;
  unsigned kc   = rki - r * 3u;

  unsigned tid  = threadIdx.x;
  unsigned wv   = tid >> 6;
  unsigned lane = tid & 63u;
  unsigned wy   = wv >> 1;
  unsigned wx   = wv & 1u;
  unsigned quad = lane >> 4;
  unsigned l16  = lane & 15u;
  unsigned rsl  = lane >> 3;
  unsigned seg  = (lane & 7u) ^ (rsl & 7u);

  unsigned h0 = ks * 8u;
  const f16* Ab = xk + (size_t)(kc * 4u + n) * 128u * XSTR + (size_t)(cseg * 64u) * XSTR
                + (h0 + 3u * r) * 64u + seg * 8u;
  const f16* Bb = xk + (size_t)(4u + n) * 128u * XSTR + (h0 + 9u) * 64u + seg * 8u;
  unsigned ar0 = wv * 16u;
  unsigned br0 = wv * 32u;

  f32x4 acc[2][4] = {};

#pragma unroll
  for (unsigned t = 0; t < 2u; t++)
    gl16(Ab + (size_t)(ar0 + t * 8u + rsl) * XSTR, &gl[(ar0 + t * 8u) * 64u]);
#pragma unroll
  for (unsigned t = 0; t < 4u; t++)
    gl16(Bb + (size_t)(br0 + t * 8u + rsl) * XSTR, &gl[4096u + (br0 + t * 8u) * 64u]);

  for (unsigned s = 0; s < 8u; s++) {
    __syncthreads();
    if (s < 7u) {
      f16* base = &gl[((s + 1u) & 1u) * 12288u];
      unsigned off = (s + 1u) * 64u;
#pragma unroll
      for (unsigned t = 0; t < 2u; t++)
        gl16(Ab + off + (size_t)(ar0 + t * 8u + rsl) * XSTR, base + (ar0 + t * 8u) * 64u);
#pragma unroll
      for (unsigned t = 0; t < 4u; t++)
        gl16(Bb + off + (size_t)(br0 + t * 8u + rsl) * XSTR, base + 4096u + (br0 + t * 8u) * 64u);
    }
    const f16* bufA = &gl[(s & 1u) * 12288u];
    const f16* bufB = bufA + 4096u;
#pragma unroll
    for (unsigned t2 = 0; t2 < 2u; t2++) {
      unsigned L = t2 * 4u + quad;
      f16x8 a[2], bb[4];
#pragma unroll
      for (int ms = 0; ms < 2; ms++) {
        unsigned rr = wy * 32u + (unsigned)ms * 16u + l16;
        a[ms] = *(const f16x8*)&bufA[rr * 64u + (L ^ (rr & 7u)) * 8u];
      }
#pragma unroll
      for (int ns = 0; ns < 4; ns++) {
        unsigned rb = wx * 64u + (unsigned)ns * 16u + l16;
        bb[ns] = *(const f16x8*)&bufB[rb * 64u + (L ^ (rb & 7u)) * 8u];
      }
#pragma unroll
      for (int ms = 0; ms < 2; ms++)
#pragma unroll
        for (int ns = 0; ns < 4; ns++)
          acc[ms][ns] = __builtin_amdgcn_mfma_f32_16x16x32_f16(a[ms], bb[ns], acc[ms][ns], 0, 0, 0);
    }
  }

  f16* tp = t3p + ((size_t)(ks * 4u + n) * 11u + rki) * 16384u;
#pragma unroll
  for (int ms = 0; ms < 2; ms++) {
#pragma unroll
    for (int ns = 0; ns < 4; ns++) {
      unsigned c0 = cseg * 64u + wy * 32u + (unsigned)ms * 16u + quad * 4u;
      unsigned d  = wx * 64u + (unsigned)ns * 16u + l16;
#pragma unroll
      for (int reg = 0; reg < 4; reg++)
        tp[(size_t)(c0 + (unsigned)reg) * 128u + d] = (f16)acc[ms][ns][reg];
    }
  }
}

// ---------------------------------------------------------------- ep: t6T = p6 * t3 (mirror for rk>=11)
__global__ __launch_bounds__(256) void ep_kernel(const f16* __restrict__ t3p,
                                                 const float* __restrict__ p6,
                                                 f16* __restrict__ t6T) {
  unsigned idx = blockIdx.x * 256u + threadIdx.x;   // < 344064
  unsigned t   = idx >> 12;                          // n*21+rk
  unsigned rk  = t % 21u;
  unsigned n   = t / 21u;

  if (rk <= 10u) {
    unsigned d4 = idx & 31u;
    unsigned c  = (idx >> 5) & 127u;
    unsigned d0 = d4 * 4u;
    float s0 = 0.f, s1 = 0.f, s2 = 0.f, s3 = 0.f;
#pragma unroll
    for (unsigned ks = 0; ks < 8u; ks++) {
      f16x4 v = *(const f16x4*)(t3p + (((size_t)(ks * 4u + n) * 11u + rk) * 16384u + c * 128u + d0));
      s0 += (float)v[0]; s1 += (float)v[1]; s2 += (float)v[2]; s3 += (float)v[3];
    }
    const float* pp = p6 + ((size_t)c * 21u + rk) * 128u + d0;
    f16* ob = t6T + (size_t)(n * 128u + d0) * 2688u + rk * 128u + c;
    ob[0]        = (f16)(s0 * pp[0]);
    ob[2688]     = (f16)(s1 * pp[1]);
    ob[2 * 2688] = (f16)(s2 * pp[2]);
    ob[3 * 2688] = (f16)(s3 * pp[3]);
  } else {
    unsigned mrk = 20u - rk;          // t3[c,rk,d] = t3p_sum[mrk][d][c]
    unsigned c4 = idx & 31u;
    unsigned d  = (idx >> 5) & 127u;
    unsigned c0 = c4 * 4u;
    float s0 = 0.f, s1 = 0.f, s2 = 0.f, s3 = 0.f;
#pragma unroll
    for (unsigned ks = 0; ks < 8u; ks++) {
      f16x4 v = *(const f16x4*)(t3p + (((size_t)(ks * 4u + n) * 11u + mrk) * 16384u + d * 128u + c0));
      s0 += (float)v[0]; s1 += (float)v[1]; s2 += (float)v[2]; s3 += (float)v[3];
    }
    f16x4 o;
    o[0] = (f16)(s0 * p6[((size_t)(c0 + 0u) * 21u + rk) * 128u + d]);
    o[1] = (f16)(s1 * p6[((size_t)(c0 + 1u) * 21u + rk) * 128u + d]);
    o[2] = (f16)(s2 * p6[((size_t)(c0 + 2u) * 21u + rk) * 128u + d]);
    o[3] = (f16)(s3 * p6[((size_t)(c0 + 3u) * 21u + rk) * 128u + d]);
    *(f16x4*)(t6T + (size_t)(n * 128u + d) * 2688u + rk * 128u + c0) = o;
  }
}

// ---------------------------------------------------------------- outp (split-K x8: g(4) x js(2))
// grid 2048 = n(4)*h(64)*g(4)*js(2) -> 8 blocks/CU; block 256 (4 waves 2x2), tile 64w x 128d.
// js owns rk range [js*11, min(21, js*11+11)); per-wave body identical to round-4/8.
#define ALDS_STR 40
#define RT_STR   72
__global__ __launch_bounds__(256, 8) void outp_kernel(const f16* __restrict__ xk,
                                                      const float* __restrict__ p5,
                                                      const f16* __restrict__ t6T,
                                                      f16* __restrict__ t8p) {
  __shared__ f16 smem[128 * RT_STR];   // 18432 B; first 10240 B = 2 staging bufs
  f16* Alds = smem;

  unsigned b  = blockIdx.x;
  unsigned js = b & 1u;
  unsigned g  = (b >> 1) & 3u;
  unsigned h  = (b >> 3) & 63u;
  unsigned n  = b >> 9;
  unsigned j0 = js * 11u;
  unsigned j1 = js ? 21u : 11u;

  unsigned tid  = threadIdx.x;
  unsigned wv   = tid >> 6;
  unsigned lane = tid & 63u;
  unsigned wy   = wv >> 1;
  unsigned wx   = wv & 1u;
  unsigned quad = lane >> 4;
  unsigned l16  = lane & 15u;
  unsigned wst  = tid & 63u;
  unsigned g8   = tid >> 6;

  unsigned cbase = g * 32u + g8 * 8u;
  const float* prow0 = p5 + (size_t)cbase * (21u * 4096u) + h * 64u + wst;
  const f16* bfb = t6T + (size_t)(n * 128u + wx * 64u + l16) * 2688u + g * 32u + quad * 8u;

  f32x4 acc[2][4] = {};
  f16 xv[8]; float pv[8];
  f16x8 bfc[4];

  { // prefetch chunk j0
    unsigned rr = j0 / 3u;
    unsigned kcc = j0 - rr * 3u;
    const f16* xrow = xk + (((size_t)(kcc * 4u + n) * 128u + cbase) * XROWS + (h + 3u * rr)) * 64u + wst;
    const float* prow = prow0 + j0 * 4096u;
#pragma unroll
    for (int i = 0; i < 8; i++) { xv[i] = xrow[(size_t)i * XSTR]; pv[i] = prow[(size_t)i * (21u * 4096u)]; }
#pragma unroll
    for (int ns = 0; ns < 4; ns++) bfc[ns] = *(const f16x8*)(bfb + (size_t)ns * 16u * 2688u + j0 * 128u);
  }

  for (unsigned j = j0; j < j1; j++) {
    f16* Ag = Alds + (j & 1u) * 2560u;
    {
      f16x8 av;
#pragma unroll
      for (int i = 0; i < 8; i++) av[i] = (f16)((float)xv[i] * (1.0f + pv[i]));
      *(f16x8*)&Ag[wst * ALDS_STR + g8 * 8u] = av;
    }
    __syncthreads();

    f16x8 bfn[4];
    if (j + 1u < j1) {   // register prefetch of chunk j+1 (overlaps MFMA below)
      unsigned rk = j + 1u;
      unsigned rr = rk / 3u;
      unsigned kcc = rk - rr * 3u;
      const f16* xrow = xk + (((size_t)(kcc * 4u + n) * 128u + cbase) * XROWS + (h + 3u * rr)) * 64u + wst;
      const float* prow = prow0 + rk * 4096u;
#pragma unroll
      for (int i = 0; i < 8; i++) { xv[i] = xrow[(size_t)i * XSTR]; pv[i] = prow[(size_t)i * (21u * 4096u)]; }
#pragma unroll
      for (int ns = 0; ns < 4; ns++) bfn[ns] = *(const f16x8*)(bfb + (size_t)ns * 16u * 2688u + rk * 128u);
    }

    f16x8 a[2];
#pragma unroll
    for (int ms = 0; ms < 2; ms++)
      a[ms] = *(const f16x8*)&Ag[(wy * 32u + (unsigned)ms * 16u + l16) * ALDS_STR + quad * 8u];
#pragma unroll
    for (int ms = 0; ms < 2; ms++)
#pragma unroll
      for (int ns = 0; ns < 4; ns++)
        acc[ms][ns] = __builtin_amdgcn_mfma_f32_16x16x32_f16(a[ms], bfc[ns], acc[ms][ns], 0, 0, 0);
#pragma unroll
    for (int ns = 0; ns < 4; ns++) bfc[ns] = bfn[ns];
  }

  // transpose via f16 LDS tile for coalesced partial stores: t8p[js*4+g][n][h][d][w]
  __syncthreads();
  f16* Rt = smem;
#pragma unroll
  for (int ms = 0; ms < 2; ms++)
#pragma unroll
    for (int ns = 0; ns < 4; ns++) {
      unsigned w0 = wy * 32u + (unsigned)ms * 16u + quad * 4u;
      unsigned d  = wx * 64u + (unsigned)ns * 16u + l16;
      f16x4 t;
#pragma unroll
      for (int reg = 0; reg < 4; reg++) t[reg] = (f16)acc[ms][ns][reg];
      *(f16x4*)&Rt[d * RT_STR + w0] = t;
    }
  __syncthreads();
  f16* op = t8p + ((size_t)(((js * 4u + g) * 4u + n) * 64u + h)) * 8192u;
#pragma unroll
  for (unsigned it = 0; it < 4u; it++) {
    unsigned row = (tid >> 3) + it * 32u;
    unsigned w0  = (tid & 7u) * 8u;
    f16x8 o = *(const f16x8*)&Rt[row * RT_STR + w0];
    *(f16x8*)(op + row * 64u + w0) = o;
  }
}

// ---------------------------------------------------------------- red: out = FS * sum_s(t8p), 8 slices
__global__ __launch_bounds__(256) void red_kernel(const f16* __restrict__ t8p,
                                                  float* __restrict__ out) {
  unsigned idx = blockIdx.x * 256u + threadIdx.x;
  unsigned w0 = (idx & 7u) * 8u;
  unsigned h  = (idx >> 3) & 63u;
  unsigned d  = (idx >> 9) & 127u;
  unsigned n  = idx >> 16;
  const float FS = 0.15430334996209192f;  // 8 / sqrt(2688)
  float s[8] = {};
#pragma unroll
  for (unsigned sl = 0; sl < 8u; sl++) {
    f16x8 v = *(const f16x8*)(t8p + ((size_t)((sl * 4u + n) * 64u + h)) * 8192u + d * 64u + w0);
#pragma unroll
    for (int i = 0; i < 8; i++) s[i] += (float)v[i];
  }
  f32x4 o0, o1;
#pragma unroll
  for (int i = 0; i < 4; i++) { o0[i] = s[i] * FS; o1[i] = s[i + 4] * FS; }
  float* op = out + ((size_t)(n * 128u + d) * 64u + h) * 64u + w0;
  *(f32x4*)op = o0;
  *(f32x4*)(op + 4) = o1;
}

// ---------------------------------------------------------------- launch
extern "C" void kernel_launch(void* const* d_in, const int* in_sizes, int n_in,
                              void* d_out, int out_size, void* d_ws, size_t ws_size,
                              hipStream_t stream) {
  const float* x  = (const float*)d_in[0];
  const float* p5 = (const float*)d_in[1];
  const float* p6 = (const float*)d_in[2];
  float* out = (float*)d_out;
  f16* xk  = (f16*)((char*)d_ws);
  f16* t6T = (f16*)((char*)d_ws + T6T_OFF);
  f16* t3p = (f16*)((char*)d_ws + T3P_OFF);
  f16* t8p = (f16*)((char*)d_ws + T8P_OFF);   // aliases t3p (dead after ep)

  unsigned prep_blocks = (3u * 4u * 128u * 82u * 32u + 255u) / 256u;  // 15744
  hipLaunchKernelGGL(prep_kernel, dim3(prep_blocks), dim3(256), 0, stream, x, xk);
  hipLaunchKernelGGL(gram_kernel, dim3(704),  dim3(256), 0, stream, xk, t3p);
  hipLaunchKernelGGL(ep_kernel,   dim3(1344), dim3(256), 0, stream, t3p, p6, t6T);
  hipLaunchKernelGGL(outp_kernel, dim3(2048), dim3(256), 0, stream, xk, p5, t6T, t8p);
  hipLaunchKernelGGL(red_kernel,  dim3(1024), dim3(256), 0, stream, t8p, out);
}

// Round 11
// 174.546 us; speedup vs baseline: 2.4469x; 2.4469x over previous
//
#include <hip/hip_runtime.h>

typedef _Float16 f16;
typedef _Float16 f16x2 __attribute__((ext_vector_type(2)));
typedef _Float16 f16x4 __attribute__((ext_vector_type(4)));
typedef _Float16 f16x8 __attribute__((ext_vector_type(8)));
typedef float    f32x4 __attribute__((ext_vector_type(4)));

// Geometry:
//   x:   (4,128,64,64) f32     p5: (128,21,64,64) f32
//   p6:  (128,21,128)  f32     out:(4,128,64,64)  f32
// Workspace:
//   xk  [3][4][128][82][64] f16 = x*(1/8), pre-shifted per kc, zero-padded rows
//   t6T [4][128][2688]      f16 = p6 * t3, d-major
//   t3p [8][4][11][128][128] f16 = split-K Gram partials, rki 0..10 ONLY
//        (t3[c,rk,d] = t3[d,20-rk,c] exactly — lag symmetry; ep mirrors rk>=11)
//   t8p [8s][4][64][128][64] f16 = split-K out partials (s=js*4+g), ALIASES t3p
#define XROWS 82
#define XSTR  (XROWS * 64)
#define XK_ELEMS (3u * 4u * 128u * (unsigned)XSTR)
static const size_t T6T_OFF   = (size_t)XK_ELEMS * 2;                 // 16.12 MB
static const size_t T6T_BYTES = (size_t)4 * 128 * 2688 * 2;           // 2.75 MB
static const size_t T3P_OFF   = T6T_OFF + T6T_BYTES;
static const size_t T8P_OFF   = T3P_OFF;   // t3p dead before outp writes t8p

__device__ __forceinline__ void gl16(const f16* g, f16* l) {
  __builtin_amdgcn_global_load_lds((const __attribute__((address_space(1))) void*)g,
                                   (__attribute__((address_space(3))) void*)l, 16, 0, 0);
}

// ---------------------------------------------------------------- prep (float2 loads)
__global__ __launch_bounds__(256) void prep_kernel(const float* __restrict__ x,
                                                   f16* __restrict__ xk) {
  unsigned p = blockIdx.x * 256u + threadIdx.x;
  unsigned total = 3u * 4u * 128u * 82u * 32u;
  if (p >= total) return;
  unsigned wp   = p & 31u;
  unsigned row  = (p >> 5) % 82u;
  unsigned rest = p / (32u * 82u);
  unsigned c    = rest & 127u;
  unsigned rest2 = rest >> 7;
  unsigned n    = rest2 & 3u;
  unsigned kc   = rest2 >> 2;
  int hsrc = (int)row - 9;
  int wsrc = (int)(wp * 2u) + 2 * (int)kc - 2;
  f16x2 v; v.x = (f16)0.f; v.y = (f16)0.f;
  if (hsrc >= 0 && hsrc < 64 && wsrc >= 0 && wsrc < 64) {
    const float2* src = (const float2*)(x + (((size_t)(n * 128u + c) * 64u + (unsigned)hsrc) * 64u + (unsigned)wsrc));
    float2 xv = *src;
    v.x = (f16)(xv.x * 0.125f);
    v.y = (f16)(xv.y * 0.125f);
  }
  ((f16x2*)xk)[p] = v;
}

// ---------------------------------------------------------------- gram (LDS-staged, rki 0..10, split-K)
// grid 704 = n(4)*rki(11)*cseg(2)*ks(8); block 256 (4 waves 2x2), tile 64c x 128d, K-slice 512, 8 steps.
__global__ __launch_bounds__(256, 3) void gram_kernel(const f16* __restrict__ xk,
                                                      f16* __restrict__ t3p) {
  __shared__ f16 gl[2 * 12288];

  unsigned b    = blockIdx.x;
  unsigned ks   = b & 7u;
  unsigned cseg = (b >> 3) & 1u;
  unsigned rki  = (b >> 4) % 11u;
  unsigned n    = b / 176u;
  unsigned r    = rki / 3u;
  unsigned kc   = rki - r * 3u;

  unsigned tid  = threadIdx.x;
  unsigned wv   = tid >> 6;
  unsigned lane = tid & 63u;
  unsigned wy   = wv >> 1;
  unsigned wx   = wv & 1u;
  unsigned quad = lane >> 4;
  unsigned l16  = lane & 15u;
  unsigned rsl  = lane >> 3;
  unsigned seg  = (lane & 7u) ^ (rsl & 7u);

  unsigned h0 = ks * 8u;
  const f16* Ab = xk + (size_t)(kc * 4u + n) * 128u * XSTR + (size_t)(cseg * 64u) * XSTR
                + (h0 + 3u * r) * 64u + seg * 8u;
  const f16* Bb = xk + (size_t)(4u + n) * 128u * XSTR + (h0 + 9u) * 64u + seg * 8u;
  unsigned ar0 = wv * 16u;
  unsigned br0 = wv * 32u;

  f32x4 acc[2][4] = {};

#pragma unroll
  for (unsigned t = 0; t < 2u; t++)
    gl16(Ab + (size_t)(ar0 + t * 8u + rsl) * XSTR, &gl[(ar0 + t * 8u) * 64u]);
#pragma unroll
  for (unsigned t = 0; t < 4u; t++)
    gl16(Bb + (size_t)(br0 + t * 8u + rsl) * XSTR, &gl[4096u + (br0 + t * 8u) * 64u]);

  for (unsigned s = 0; s < 8u; s++) {
    __syncthreads();
    if (s < 7u) {
      f16* base = &gl[((s + 1u) & 1u) * 12288u];
      unsigned off = (s + 1u) * 64u;
#pragma unroll
      for (unsigned t = 0; t < 2u; t++)
        gl16(Ab + off + (size_t)(ar0 + t * 8u + rsl) * XSTR, base + (ar0 + t * 8u) * 64u);
#pragma unroll
      for (unsigned t = 0; t < 4u; t++)
        gl16(Bb + off + (size_t)(br0 + t * 8u + rsl) * XSTR, base + 4096u + (br0 + t * 8u) * 64u);
    }
    const f16* bufA = &gl[(s & 1u) * 12288u];
    const f16* bufB = bufA + 4096u;
#pragma unroll
    for (unsigned t2 = 0; t2 < 2u; t2++) {
      unsigned L = t2 * 4u + quad;
      f16x8 a[2], bb[4];
#pragma unroll
      for (int ms = 0; ms < 2; ms++) {
        unsigned rr = wy * 32u + (unsigned)ms * 16u + l16;
        a[ms] = *(const f16x8*)&bufA[rr * 64u + (L ^ (rr & 7u)) * 8u];
      }
#pragma unroll
      for (int ns = 0; ns < 4; ns++) {
        unsigned rb = wx * 64u + (unsigned)ns * 16u + l16;
        bb[ns] = *(const f16x8*)&bufB[rb * 64u + (L ^ (rb & 7u)) * 8u];
      }
#pragma unroll
      for (int ms = 0; ms < 2; ms++)
#pragma unroll
        for (int ns = 0; ns < 4; ns++)
          acc[ms][ns] = __builtin_amdgcn_mfma_f32_16x16x32_f16(a[ms], bb[ns], acc[ms][ns], 0, 0, 0);
    }
  }

  f16* tp = t3p + ((size_t)(ks * 4u + n) * 11u + rki) * 16384u;
#pragma unroll
  for (int ms = 0; ms < 2; ms++) {
#pragma unroll
    for (int ns = 0; ns < 4; ns++) {
      unsigned c0 = cseg * 64u + wy * 32u + (unsigned)ms * 16u + quad * 4u;
      unsigned d  = wx * 64u + (unsigned)ns * 16u + l16;
#pragma unroll
      for (int reg = 0; reg < 4; reg++)
        tp[(size_t)(c0 + (unsigned)reg) * 128u + d] = (f16)acc[ms][ns][reg];
    }
  }
}

// ---------------------------------------------------------------- ep: t6T = p6 * t3 (mirror for rk>=11)
__global__ __launch_bounds__(256) void ep_kernel(const f16* __restrict__ t3p,
                                                 const float* __restrict__ p6,
                                                 f16* __restrict__ t6T) {
  unsigned idx = blockIdx.x * 256u + threadIdx.x;   // < 344064
  unsigned t   = idx >> 12;                          // n*21+rk
  unsigned rk  = t % 21u;
  unsigned n   = t / 21u;

  if (rk <= 10u) {
    unsigned d4 = idx & 31u;
    unsigned c  = (idx >> 5) & 127u;
    unsigned d0 = d4 * 4u;
    float s0 = 0.f, s1 = 0.f, s2 = 0.f, s3 = 0.f;
#pragma unroll
    for (unsigned ks = 0; ks < 8u; ks++) {
      f16x4 v = *(const f16x4*)(t3p + (((size_t)(ks * 4u + n) * 11u + rk) * 16384u + c * 128u + d0));
      s0 += (float)v[0]; s1 += (float)v[1]; s2 += (float)v[2]; s3 += (float)v[3];
    }
    const float* pp = p6 + ((size_t)c * 21u + rk) * 128u + d0;
    f16* ob = t6T + (size_t)(n * 128u + d0) * 2688u + rk * 128u + c;
    ob[0]        = (f16)(s0 * pp[0]);
    ob[2688]     = (f16)(s1 * pp[1]);
    ob[2 * 2688] = (f16)(s2 * pp[2]);
    ob[3 * 2688] = (f16)(s3 * pp[3]);
  } else {
    unsigned mrk = 20u - rk;          // t3[c,rk,d] = t3p_sum[mrk][d][c]
    unsigned c4 = idx & 31u;
    unsigned d  = (idx >> 5) & 127u;
    unsigned c0 = c4 * 4u;
    float s0 = 0.f, s1 = 0.f, s2 = 0.f, s3 = 0.f;
#pragma unroll
    for (unsigned ks = 0; ks < 8u; ks++) {
      f16x4 v = *(const f16x4*)(t3p + (((size_t)(ks * 4u + n) * 11u + mrk) * 16384u + d * 128u + c0));
      s0 += (float)v[0]; s1 += (float)v[1]; s2 += (float)v[2]; s3 += (float)v[3];
    }
    f16x4 o;
    o[0] = (f16)(s0 * p6[((size_t)(c0 + 0u) * 21u + rk) * 128u + d]);
    o[1] = (f16)(s1 * p6[((size_t)(c0 + 1u) * 21u + rk) * 128u + d]);
    o[2] = (f16)(s2 * p6[((size_t)(c0 + 2u) * 21u + rk) * 128u + d]);
    o[3] = (f16)(s3 * p6[((size_t)(c0 + 3u) * 21u + rk) * 128u + d]);
    *(f16x4*)(t6T + (size_t)(n * 128u + d) * 2688u + rk * 128u + c0) = o;
  }
}

// ---------------------------------------------------------------- outp (split-K x8: g(4) x js(2))
// grid 2048 = n(4)*h(64)*g(4)*js(2); block 256 (4 waves 2x2), tile 64w x 128d.
// __launch_bounds__(256,4): compiler targets <=128 VGPR (natural 60, no spill);
// actual VGPR=60 <= 64 lets HW run 8 blocks/CU from the 2048-block grid.
// (round-10 lesson: (256,8) forced 32 VGPR -> full acc spill, 1.2 GB scratch traffic)
#define ALDS_STR 40
#define RT_STR   72
__global__ __launch_bounds__(256, 4) void outp_kernel(const f16* __restrict__ xk,
                                                      const float* __restrict__ p5,
                                                      const f16* __restrict__ t6T,
                                                      f16* __restrict__ t8p) {
  __shared__ f16 smem[128 * RT_STR];   // 18432 B; first 10240 B = 2 staging bufs
  f16* Alds = smem;

  unsigned b  = blockIdx.x;
  unsigned js = b & 1u;
  unsigned g  = (b >> 1) & 3u;
  unsigned h  = (b >> 3) & 63u;
  unsigned n  = b >> 9;
  unsigned j0 = js * 11u;
  unsigned j1 = js ? 21u : 11u;

  unsigned tid  = threadIdx.x;
  unsigned wv   = tid >> 6;
  unsigned lane = tid & 63u;
  unsigned wy   = wv >> 1;
  unsigned wx   = wv & 1u;
  unsigned quad = lane >> 4;
  unsigned l16  = lane & 15u;
  unsigned wst  = tid & 63u;
  unsigned g8   = tid >> 6;

  unsigned cbase = g * 32u + g8 * 8u;
  const float* prow0 = p5 + (size_t)cbase * (21u * 4096u) + h * 64u + wst;
  const f16* bfb = t6T + (size_t)(n * 128u + wx * 64u + l16) * 2688u + g * 32u + quad * 8u;

  f32x4 acc[2][4] = {};
  f16 xv[8]; float pv[8];
  f16x8 bfc[4];

  { // prefetch chunk j0
    unsigned rr = j0 / 3u;
    unsigned kcc = j0 - rr * 3u;
    const f16* xrow = xk + (((size_t)(kcc * 4u + n) * 128u + cbase) * XROWS + (h + 3u * rr)) * 64u + wst;
    const float* prow = prow0 + j0 * 4096u;
#pragma unroll
    for (int i = 0; i < 8; i++) { xv[i] = xrow[(size_t)i * XSTR]; pv[i] = prow[(size_t)i * (21u * 4096u)]; }
#pragma unroll
    for (int ns = 0; ns < 4; ns++) bfc[ns] = *(const f16x8*)(bfb + (size_t)ns * 16u * 2688u + j0 * 128u);
  }

  for (unsigned j = j0; j < j1; j++) {
    f16* Ag = Alds + (j & 1u) * 2560u;
    {
      f16x8 av;
#pragma unroll
      for (int i = 0; i < 8; i++) av[i] = (f16)((float)xv[i] * (1.0f + pv[i]));
      *(f16x8*)&Ag[wst * ALDS_STR + g8 * 8u] = av;
    }
    __syncthreads();

    f16x8 bfn[4];
    if (j + 1u < j1) {   // register prefetch of chunk j+1 (overlaps MFMA below)
      unsigned rk = j + 1u;
      unsigned rr = rk / 3u;
      unsigned kcc = rk - rr * 3u;
      const f16* xrow = xk + (((size_t)(kcc * 4u + n) * 128u + cbase) * XROWS + (h + 3u * rr)) * 64u + wst;
      const float* prow = prow0 + rk * 4096u;
#pragma unroll
      for (int i = 0; i < 8; i++) { xv[i] = xrow[(size_t)i * XSTR]; pv[i] = prow[(size_t)i * (21u * 4096u)]; }
#pragma unroll
      for (int ns = 0; ns < 4; ns++) bfn[ns] = *(const f16x8*)(bfb + (size_t)ns * 16u * 2688u + rk * 128u);
    }

    f16x8 a[2];
#pragma unroll
    for (int ms = 0; ms < 2; ms++)
      a[ms] = *(const f16x8*)&Ag[(wy * 32u + (unsigned)ms * 16u + l16) * ALDS_STR + quad * 8u];
#pragma unroll
    for (int ms = 0; ms < 2; ms++)
#pragma unroll
      for (int ns = 0; ns < 4; ns++)
        acc[ms][ns] = __builtin_amdgcn_mfma_f32_16x16x32_f16(a[ms], bfc[ns], acc[ms][ns], 0, 0, 0);
#pragma unroll
    for (int ns = 0; ns < 4; ns++) bfc[ns] = bfn[ns];
  }

  // transpose via f16 LDS tile for coalesced partial stores: t8p[js*4+g][n][h][d][w]
  __syncthreads();
  f16* Rt = smem;
#pragma unroll
  for (int ms = 0; ms < 2; ms++)
#pragma unroll
    for (int ns = 0; ns < 4; ns++) {
      unsigned w0 = wy * 32u + (unsigned)ms * 16u + quad * 4u;
      unsigned d  = wx * 64u + (unsigned)ns * 16u + l16;
      f16x4 t;
#pragma unroll
      for (int reg = 0; reg < 4; reg++) t[reg] = (f16)acc[ms][ns][reg];
      *(f16x4*)&Rt[d * RT_STR + w0] = t;
    }
  __syncthreads();
  f16* op = t8p + ((size_t)(((js * 4u + g) * 4u + n) * 64u + h)) * 8192u;
#pragma unroll
  for (unsigned it = 0; it < 4u; it++) {
    unsigned row = (tid >> 3) + it * 32u;
    unsigned w0  = (tid & 7u) * 8u;
    f16x8 o = *(const f16x8*)&Rt[row * RT_STR + w0];
    *(f16x8*)(op + row * 64u + w0) = o;
  }
}

// ---------------------------------------------------------------- red: out = FS * sum_s(t8p), 8 slices
__global__ __launch_bounds__(256) void red_kernel(const f16* __restrict__ t8p,
                                                  float* __restrict__ out) {
  unsigned idx = blockIdx.x * 256u + threadIdx.x;
  unsigned w0 = (idx & 7u) * 8u;
  unsigned h  = (idx >> 3) & 63u;
  unsigned d  = (idx >> 9) & 127u;
  unsigned n  = idx >> 16;
  const float FS = 0.15430334996209192f;  // 8 / sqrt(2688)
  float s[8] = {};
#pragma unroll
  for (unsigned sl = 0; sl < 8u; sl++) {
    f16x8 v = *(const f16x8*)(t8p + ((size_t)((sl * 4u + n) * 64u + h)) * 8192u + d * 64u + w0);
#pragma unroll
    for (int i = 0; i < 8; i++) s[i] += (float)v[i];
  }
  f32x4 o0, o1;
#pragma unroll
  for (int i = 0; i < 4; i++) { o0[i] = s[i] * FS; o1[i] = s[i + 4] * FS; }
  float* op = out + ((size_t)(n * 128u + d) * 64u + h) * 64u + w0;
  *(f32x4*)op = o0;
  *(f32x4*)(op + 4) = o1;
}

// ---------------------------------------------------------------- launch
extern "C" void kernel_launch(void* const* d_in, const int* in_sizes, int n_in,
                              void* d_out, int out_size, void* d_ws, size_t ws_size,
                              hipStream_t stream) {
  const float* x  = (const float*)d_in[0];
  const float* p5 = (const float*)d_in[1];
  const float* p6 = (const float*)d_in[2];
  float* out = (float*)d_out;
  f16* xk  = (f16*)((char*)d_ws);
  f16* t6T = (f16*)((char*)d_ws + T6T_OFF);
  f16* t3p = (f16*)((char*)d_ws + T3P_OFF);
  f16* t8p = (f16*)((char*)d_ws + T8P_OFF);   // aliases t3p (dead after ep)

  unsigned prep_blocks = (3u * 4u * 128u * 82u * 32u + 255u) / 256u;  // 15744
  hipLaunchKernelGGL(prep_kernel, dim3(prep_blocks), dim3(256), 0, stream, x, xk);
  hipLaunchKernelGGL(gram_kernel, dim3(704),  dim3(256), 0, stream, xk, t3p);
  hipLaunchKernelGGL(ep_kernel,   dim3(1344), dim3(256), 0, stream, t3p, p6, t6T);
  hipLaunchKernelGGL(outp_kernel, dim3(2048), dim3(256), 0, stream, xk, p5, t6T, t8p);
  hipLaunchKernelGGL(red_kernel,  dim3(1024), dim3(256), 0, stream, t8p, out);
}

// Round 12
// 174.210 us; speedup vs baseline: 2.4516x; 1.0019x over previous
//
#include <hip/hip_runtime.h>

typedef _Float16 f16;
typedef _Float16 f16x2 __attribute__((ext_vector_type(2)));
typedef _Float16 f16x4 __attribute__((ext_vector_type(4)));
typedef _Float16 f16x8 __attribute__((ext_vector_type(8)));
typedef float    f32x4 __attribute__((ext_vector_type(4)));

// Geometry:
//   x:   (4,128,64,64) f32     p5: (128,21,64,64) f32
//   p6:  (128,21,128)  f32     out:(4,128,64,64)  f32
// Workspace (~57.7 MB):
//   xk  [3][4][128][82][64] f16 = x*(1/8), pre-shifted per kc, zero-padded rows
//   t6T [4][128][2688]      f16 = p6 * t3, d-major
//   q5  [128][21][64][64]   f16 = 1 + p5 (same layout as p5)
//   t3p [8][4][11][128][128] f16 = split-K Gram partials, rki 0..10 ONLY
//        (t3[c,rk,d] = t3[d,20-rk,c] exactly — lag symmetry; ep mirrors rk>=11)
//   t8p [4][4][64][128][64]  f16 = split-K out partials (g,n,h,d,w), ALIASES t3p
#define XROWS 82
#define XSTR  (XROWS * 64)
#define XK_ELEMS (3u * 4u * 128u * (unsigned)XSTR)
static const size_t T6T_OFF = (size_t)XK_ELEMS * 2;                 // 16,121,856
static const size_t Q5_OFF  = T6T_OFF + (size_t)4 * 128 * 2688 * 2; // +2,752,512
static const size_t T3P_OFF = Q5_OFF + (size_t)128 * 21 * 4096 * 2; // +22,020,096
static const size_t T8P_OFF = T3P_OFF;   // t3p dead before outp writes t8p

__device__ __forceinline__ void gl16(const f16* g, f16* l) {
  __builtin_amdgcn_global_load_lds((const __attribute__((address_space(1))) void*)g,
                                   (__attribute__((address_space(3))) void*)l, 16, 0, 0);
}

// ---------------------------------------------------------------- prep (xk; float2 loads — r8-proven)
__global__ __launch_bounds__(256) void prep_kernel(const float* __restrict__ x,
                                                   f16* __restrict__ xk) {
  unsigned p = blockIdx.x * 256u + threadIdx.x;
  unsigned total = 3u * 4u * 128u * 82u * 32u;
  if (p >= total) return;
  unsigned wp   = p & 31u;
  unsigned row  = (p >> 5) % 82u;
  unsigned rest = p / (32u * 82u);
  unsigned c    = rest & 127u;
  unsigned rest2 = rest >> 7;
  unsigned n    = rest2 & 3u;
  unsigned kc   = rest2 >> 2;
  int hsrc = (int)row - 9;
  int wsrc = (int)(wp * 2u) + 2 * (int)kc - 2;
  f16x2 v; v.x = (f16)0.f; v.y = (f16)0.f;
  if (hsrc >= 0 && hsrc < 64 && wsrc >= 0 && wsrc < 64) {
    const float2* src = (const float2*)(x + (((size_t)(n * 128u + c) * 64u + (unsigned)hsrc) * 64u + (unsigned)wsrc));
    float2 xv = *src;
    v.x = (f16)(xv.x * 0.125f);
    v.y = (f16)(xv.y * 0.125f);
  }
  ((f16x2*)xk)[p] = v;
}

// ---------------------------------------------------------------- prepQ: q5 = (f16)(1 + p5), streaming
// grid 5376 = 11,010,048 elems / (256 thr * 8); two aligned float4 loads + one f16x8 store per thread.
__global__ __launch_bounds__(256) void prepQ_kernel(const float* __restrict__ p5,
                                                    f16* __restrict__ q5) {
  unsigned p = blockIdx.x * 256u + threadIdx.x;   // f16x8 group index (exact)
  const float* src = p5 + (size_t)p * 8u;
  f32x4 a = *(const f32x4*)src;
  f32x4 b = *(const f32x4*)(src + 4);
  f16x8 o;
#pragma unroll
  for (int i = 0; i < 4; i++) o[i] = (f16)(1.0f + a[i]);
#pragma unroll
  for (int i = 0; i < 4; i++) o[4 + i] = (f16)(1.0f + b[i]);
  *(f16x8*)(q5 + (size_t)p * 8u) = o;
}

// ---------------------------------------------------------------- gram (LDS-staged, rki 0..10, split-K)
// grid 704 = n(4)*rki(11)*cseg(2)*ks(8); block 256 (4 waves 2x2), tile 64c x 128d, K-slice 512, 8 steps.
__global__ __launch_bounds__(256, 3) void gram_kernel(const f16* __restrict__ xk,
                                                      f16* __restrict__ t3p) {
  __shared__ f16 gl[2 * 12288];

  unsigned b    = blockIdx.x;
  unsigned ks   = b & 7u;
  unsigned cseg = (b >> 3) & 1u;
  unsigned rki  = (b >> 4) % 11u;
  unsigned n    = b / 176u;
  unsigned r    = rki / 3u;
  unsigned kc   = rki - r * 3u;

  unsigned tid  = threadIdx.x;
  unsigned wv   = tid >> 6;
  unsigned lane = tid & 63u;
  unsigned wy   = wv >> 1;
  unsigned wx   = wv & 1u;
  unsigned quad = lane >> 4;
  unsigned l16  = lane & 15u;
  unsigned rsl  = lane >> 3;
  unsigned seg  = (lane & 7u) ^ (rsl & 7u);

  unsigned h0 = ks * 8u;
  const f16* Ab = xk + (size_t)(kc * 4u + n) * 128u * XSTR + (size_t)(cseg * 64u) * XSTR
                + (h0 + 3u * r) * 64u + seg * 8u;
  const f16* Bb = xk + (size_t)(4u + n) * 128u * XSTR + (h0 + 9u) * 64u + seg * 8u;
  unsigned ar0 = wv * 16u;
  unsigned br0 = wv * 32u;

  f32x4 acc[2][4] = {};

#pragma unroll
  for (unsigned t = 0; t < 2u; t++)
    gl16(Ab + (size_t)(ar0 + t * 8u + rsl) * XSTR, &gl[(ar0 + t * 8u) * 64u]);
#pragma unroll
  for (unsigned t = 0; t < 4u; t++)
    gl16(Bb + (size_t)(br0 + t * 8u + rsl) * XSTR, &gl[4096u + (br0 + t * 8u) * 64u]);

  for (unsigned s = 0; s < 8u; s++) {
    __syncthreads();
    if (s < 7u) {
      f16* base = &gl[((s + 1u) & 1u) * 12288u];
      unsigned off = (s + 1u) * 64u;
#pragma unroll
      for (unsigned t = 0; t < 2u; t++)
        gl16(Ab + off + (size_t)(ar0 + t * 8u + rsl) * XSTR, base + (ar0 + t * 8u) * 64u);
#pragma unroll
      for (unsigned t = 0; t < 4u; t++)
        gl16(Bb + off + (size_t)(br0 + t * 8u + rsl) * XSTR, base + 4096u + (br0 + t * 8u) * 64u);
    }
    const f16* bufA = &gl[(s & 1u) * 12288u];
    const f16* bufB = bufA + 4096u;
#pragma unroll
    for (unsigned t2 = 0; t2 < 2u; t2++) {
      unsigned L = t2 * 4u + quad;
      f16x8 a[2], bb[4];
#pragma unroll
      for (int ms = 0; ms < 2; ms++) {
        unsigned rr = wy * 32u + (unsigned)ms * 16u + l16;
        a[ms] = *(const f16x8*)&bufA[rr * 64u + (L ^ (rr & 7u)) * 8u];
      }
#pragma unroll
      for (int ns = 0; ns < 4; ns++) {
        unsigned rb = wx * 64u + (unsigned)ns * 16u + l16;
        bb[ns] = *(const f16x8*)&bufB[rb * 64u + (L ^ (rb & 7u)) * 8u];
      }
#pragma unroll
      for (int ms = 0; ms < 2; ms++)
#pragma unroll
        for (int ns = 0; ns < 4; ns++)
          acc[ms][ns] = __builtin_amdgcn_mfma_f32_16x16x32_f16(a[ms], bb[ns], acc[ms][ns], 0, 0, 0);
    }
  }

  f16* tp = t3p + ((size_t)(ks * 4u + n) * 11u + rki) * 16384u;
#pragma unroll
  for (int ms = 0; ms < 2; ms++) {
#pragma unroll
    for (int ns = 0; ns < 4; ns++) {
      unsigned c0 = cseg * 64u + wy * 32u + (unsigned)ms * 16u + quad * 4u;
      unsigned d  = wx * 64u + (unsigned)ns * 16u + l16;
#pragma unroll
      for (int reg = 0; reg < 4; reg++)
        tp[(size_t)(c0 + (unsigned)reg) * 128u + d] = (f16)acc[ms][ns][reg];
    }
  }
}

// ---------------------------------------------------------------- ep: t6T = p6 * t3 (mirror for rk>=11)
__global__ __launch_bounds__(256) void ep_kernel(const f16* __restrict__ t3p,
                                                 const float* __restrict__ p6,
                                                 f16* __restrict__ t6T) {
  unsigned idx = blockIdx.x * 256u + threadIdx.x;   // < 344064
  unsigned t   = idx >> 12;                          // n*21+rk
  unsigned rk  = t % 21u;
  unsigned n   = t / 21u;

  if (rk <= 10u) {
    unsigned d4 = idx & 31u;
    unsigned c  = (idx >> 5) & 127u;
    unsigned d0 = d4 * 4u;
    float s0 = 0.f, s1 = 0.f, s2 = 0.f, s3 = 0.f;
#pragma unroll
    for (unsigned ks = 0; ks < 8u; ks++) {
      f16x4 v = *(const f16x4*)(t3p + (((size_t)(ks * 4u + n) * 11u + rk) * 16384u + c * 128u + d0));
      s0 += (float)v[0]; s1 += (float)v[1]; s2 += (float)v[2]; s3 += (float)v[3];
    }
    const float* pp = p6 + ((size_t)c * 21u + rk) * 128u + d0;
    f16* ob = t6T + (size_t)(n * 128u + d0) * 2688u + rk * 128u + c;
    ob[0]        = (f16)(s0 * pp[0]);
    ob[2688]     = (f16)(s1 * pp[1]);
    ob[2 * 2688] = (f16)(s2 * pp[2]);
    ob[3 * 2688] = (f16)(s3 * pp[3]);
  } else {
    unsigned mrk = 20u - rk;          // t3[c,rk,d] = t3p_sum[mrk][d][c]
    unsigned c4 = idx & 31u;
    unsigned d  = (idx >> 5) & 127u;
    unsigned c0 = c4 * 4u;
    float s0 = 0.f, s1 = 0.f, s2 = 0.f, s3 = 0.f;
#pragma unroll
    for (unsigned ks = 0; ks < 8u; ks++) {
      f16x4 v = *(const f16x4*)(t3p + (((size_t)(ks * 4u + n) * 11u + mrk) * 16384u + d * 128u + c0));
      s0 += (float)v[0]; s1 += (float)v[1]; s2 += (float)v[2]; s3 += (float)v[3];
    }
    f16x4 o;
    o[0] = (f16)(s0 * p6[((size_t)(c0 + 0u) * 21u + rk) * 128u + d]);
    o[1] = (f16)(s1 * p6[((size_t)(c0 + 1u) * 21u + rk) * 128u + d]);
    o[2] = (f16)(s2 * p6[((size_t)(c0 + 2u) * 21u + rk) * 128u + d]);
    o[3] = (f16)(s3 * p6[((size_t)(c0 + 3u) * 21u + rk) * 128u + d]);
    *(f16x4*)(t6T + (size_t)(n * 128u + d) * 2688u + rk * 128u + c0) = o;
  }
}

// ---------------------------------------------------------------- outp (r9 shape + q5-f16 staging)
// grid 1024 = n(4)*h(64)*g(4); block 256 (4 waves 2x2), tile 64w x 128d, j 0..21.
// q5 = (1+p5) f16: halves p-operand L2-miss bytes; modulate = packed f16 mul.
// launch_bounds(256,4): natural VGPR ~56, no spill (r10 lesson: never force 8).
#define ALDS_STR 40
#define RT_STR   72
__global__ __launch_bounds__(256, 4) void outp_kernel(const f16* __restrict__ xk,
                                                      const f16* __restrict__ q5,
                                                      const f16* __restrict__ t6T,
                                                      f16* __restrict__ t8p) {
  __shared__ f16 smem[128 * RT_STR];   // 18432 B; first 10240 B = 2 staging bufs
  f16* Alds = smem;

  unsigned b = blockIdx.x;
  unsigned g = b & 3u;
  unsigned h = (b >> 2) & 63u;
  unsigned n = b >> 8;

  unsigned tid  = threadIdx.x;
  unsigned wv   = tid >> 6;
  unsigned lane = tid & 63u;
  unsigned wy   = wv >> 1;
  unsigned wx   = wv & 1u;
  unsigned quad = lane >> 4;
  unsigned l16  = lane & 15u;
  unsigned wst  = tid & 63u;
  unsigned g8   = tid >> 6;

  unsigned cbase = g * 32u + g8 * 8u;
  const f16* qrow0 = q5 + (size_t)cbase * (21u * 4096u) + h * 64u + wst;
  const f16* bfb = t6T + (size_t)(n * 128u + wx * 64u + l16) * 2688u + g * 32u + quad * 8u;

  f32x4 acc[2][4] = {};
  f16 xv[8], qv[8];
  f16x8 bfc[4];

  { // prefetch chunk 0 (rk=0 -> r=0, kc=0)
    const f16* xrow = xk + (((size_t)n * 128u + cbase) * XROWS + h) * 64u + wst;
#pragma unroll
    for (int i = 0; i < 8; i++) { xv[i] = xrow[(size_t)i * XSTR]; qv[i] = qrow0[(size_t)i * (21u * 4096u)]; }
#pragma unroll
    for (int ns = 0; ns < 4; ns++) bfc[ns] = *(const f16x8*)(bfb + (size_t)ns * 16u * 2688u);
  }

  for (unsigned j = 0; j < 21u; j++) {
    f16* Ag = Alds + (j & 1u) * 2560u;
    {
      f16x8 av;
#pragma unroll
      for (int i = 0; i < 8; i++) av[i] = xv[i] * qv[i];   // packed f16 mul
      *(f16x8*)&Ag[wst * ALDS_STR + g8 * 8u] = av;
    }
    __syncthreads();

    f16x8 bfn[4];
    if (j < 20u) {   // register prefetch of chunk j+1 (overlaps MFMA below)
      unsigned rk = j + 1u;
      unsigned rr = rk / 3u;
      unsigned kcc = rk - rr * 3u;
      const f16* xrow = xk + (((size_t)(kcc * 4u + n) * 128u + cbase) * XROWS + (h + 3u * rr)) * 64u + wst;
      const f16* qrow = qrow0 + rk * 4096u;
#pragma unroll
      for (int i = 0; i < 8; i++) { xv[i] = xrow[(size_t)i * XSTR]; qv[i] = qrow[(size_t)i * (21u * 4096u)]; }
#pragma unroll
      for (int ns = 0; ns < 4; ns++) bfn[ns] = *(const f16x8*)(bfb + (size_t)ns * 16u * 2688u + rk * 128u);
    }

    f16x8 a[2];
#pragma unroll
    for (int ms = 0; ms < 2; ms++)
      a[ms] = *(const f16x8*)&Ag[(wy * 32u + (unsigned)ms * 16u + l16) * ALDS_STR + quad * 8u];
#pragma unroll
    for (int ms = 0; ms < 2; ms++)
#pragma unroll
      for (int ns = 0; ns < 4; ns++)
        acc[ms][ns] = __builtin_amdgcn_mfma_f32_16x16x32_f16(a[ms], bfc[ns], acc[ms][ns], 0, 0, 0);
#pragma unroll
    for (int ns = 0; ns < 4; ns++) bfc[ns] = bfn[ns];
  }

  // transpose via f16 LDS tile for coalesced partial stores: t8p[g][n][h][d][w]
  __syncthreads();
  f16* Rt = smem;
#pragma unroll
  for (int ms = 0; ms < 2; ms++)
#pragma unroll
    for (int ns = 0; ns < 4; ns++) {
      unsigned w0 = wy * 32u + (unsigned)ms * 16u + quad * 4u;
      unsigned d  = wx * 64u + (unsigned)ns * 16u + l16;
      f16x4 t;
#pragma unroll
      for (int reg = 0; reg < 4; reg++) t[reg] = (f16)acc[ms][ns][reg];
      *(f16x4*)&Rt[d * RT_STR + w0] = t;
    }
  __syncthreads();
  f16* op = t8p + ((size_t)((g * 4u + n) * 64u + h)) * 8192u;
#pragma unroll
  for (unsigned it = 0; it < 4u; it++) {
    unsigned row = (tid >> 3) + it * 32u;
    unsigned w0  = (tid & 7u) * 8u;
    f16x8 o = *(const f16x8*)&Rt[row * RT_STR + w0];
    *(f16x8*)(op + row * 64u + w0) = o;
  }
}

// ---------------------------------------------------------------- red: out = FS * sum_g(t8p), 4 slices
__global__ __launch_bounds__(256) void red_kernel(const f16* __restrict__ t8p,
                                                  float* __restrict__ out) {
  unsigned idx = blockIdx.x * 256u + threadIdx.x;
  unsigned w0 = (idx & 7u) * 8u;
  unsigned h  = (idx >> 3) & 63u;
  unsigned d  = (idx >> 9) & 127u;
  unsigned n  = idx >> 16;
  const float FS = 0.15430334996209192f;  // 8 / sqrt(2688)
  float s[8] = {};
#pragma unroll
  for (unsigned g = 0; g < 4u; g++) {
    f16x8 v = *(const f16x8*)(t8p + ((size_t)((g * 4u + n) * 64u + h)) * 8192u + d * 64u + w0);
#pragma unroll
    for (int i = 0; i < 8; i++) s[i] += (float)v[i];
  }
  f32x4 o0, o1;
#pragma unroll
  for (int i = 0; i < 4; i++) { o0[i] = s[i] * FS; o1[i] = s[i + 4] * FS; }
  float* op = out + ((size_t)(n * 128u + d) * 64u + h) * 64u + w0;
  *(f32x4*)op = o0;
  *(f32x4*)(op + 4) = o1;
}

// ---------------------------------------------------------------- launch
extern "C" void kernel_launch(void* const* d_in, const int* in_sizes, int n_in,
                              void* d_out, int out_size, void* d_ws, size_t ws_size,
                              hipStream_t stream) {
  const float* x  = (const float*)d_in[0];
  const float* p5 = (const float*)d_in[1];
  const float* p6 = (const float*)d_in[2];
  float* out = (float*)d_out;
  f16* xk  = (f16*)((char*)d_ws);
  f16* t6T = (f16*)((char*)d_ws + T6T_OFF);
  f16* q5  = (f16*)((char*)d_ws + Q5_OFF);
  f16* t3p = (f16*)((char*)d_ws + T3P_OFF);
  f16* t8p = (f16*)((char*)d_ws + T8P_OFF);   // aliases t3p (dead after ep)

  unsigned prep_blocks = (3u * 4u * 128u * 82u * 32u + 255u) / 256u;  // 15744
  hipLaunchKernelGGL(prep_kernel,  dim3(prep_blocks), dim3(256), 0, stream, x, xk);
  hipLaunchKernelGGL(prepQ_kernel, dim3(5376), dim3(256), 0, stream, p5, q5);
  hipLaunchKernelGGL(gram_kernel,  dim3(704),  dim3(256), 0, stream, xk, t3p);
  hipLaunchKernelGGL(ep_kernel,    dim3(1344), dim3(256), 0, stream, t3p, p6, t6T);
  hipLaunchKernelGGL(outp_kernel,  dim3(1024), dim3(256), 0, stream, xk, q5, t6T, t8p);
  hipLaunchKernelGGL(red_kernel,   dim3(1024), dim3(256), 0, stream, t8p, out);
}